// Round 12
// baseline (189.247 us; speedup 1.0000x reference)
//
#include <hip/hip_runtime.h>
#include <math.h>

// ToyModel: B=4, S=2048, E=256, H=512, VOCAB=50257.
// Inputs/output f32; intermediates bf16; MFMA bf16 w/ f32 accum. posneg == identity.
//
// Round 20: QK write-amplification fix. r15 PMC: QK WRITE_SIZE 77MB vs 33.5MB
// logical sc (2.3x) — the CMODE=3 epilogue stored 32-B runs scattered across
// row groups (partial-line HBM write-back). Now the C-tile goes through LDS
// like the vT repack: wm==h waves fill T[64][BN+8] with exp values (rs f32
// partials unchanged), then all threads stream the half out in full-row
// u16x8 runs (512 B/row, line-covered). Two halves, 4 barriers.
// Rest unchanged from r19 (186.8us): stage 2 TM=4 NT=4 KSUB=2 (32 MFMA/
// barrier), stages 1/4 KSUB=2, CMODE=4 epilogue-smem normalizer.
//
// ws: q@0 | k@8MiB | vT@16MiB | sc@24MiB(32MiB) | lsum@56MiB(512KB).
// embB aliases sc (dead before sc written).

typedef unsigned short u16;
typedef u16   u16x8 __attribute__((ext_vector_type(8)));
typedef short s16x8 __attribute__((ext_vector_type(8)));
typedef float f32x4 __attribute__((ext_vector_type(4)));
typedef float f32x8 __attribute__((ext_vector_type(8)));

static __device__ __forceinline__ u16 f2bf(float f) {
    unsigned u = __builtin_bit_cast(unsigned, f);
    u = (u + 0x7fffu + ((u >> 16) & 1u)) >> 16;   // RNE
    return (u16)u;
}

static __device__ __forceinline__ void gload_lds16(const u16* g, u16* l) {
    __builtin_amdgcn_global_load_lds(
        (const __attribute__((address_space(1))) void*)g,
        (__attribute__((address_space(3))) void*)l, 16, 0, 0);
}

struct PArgs {
    const float* wsrc[4];
    u16*         wdst[4];
    int          wK[4];
    const float* emb;
    const int*   tok;
    u16*         embB;
};

// z<4: f32 W[K][512] -> bf16 WT[512][K]. z>=4: XCD-striped gather+cvt of emb rows.
__launch_bounds__(256)
__global__ void prep_k(PArgs p)
{
    const int z = blockIdx.z;
    if (z < 4) {
        const float* W = p.wsrc[z];
        u16* WT = p.wdst[z];
        const int K = p.wK[z];
        const int c0 = blockIdx.x * 64;
        const int r0 = blockIdx.y * 64;
        if (r0 >= K) return;
        __shared__ float T[64][65];
        const int t = threadIdx.x;
        const int col = t & 63;
        const int rb  = t >> 6;
#pragma unroll
        for (int i = 0; i < 16; ++i)
            T[i * 4 + rb][col] = W[(long)(r0 + i * 4 + rb) * 512 + c0 + col];
        __syncthreads();
#pragma unroll
        for (int i = 0; i < 16; ++i) {
            const int orow = i * 4 + rb;
            WT[(long)(c0 + orow) * K + r0 + col] = f2bf(T[col][orow]);
        }
    } else {
        const int b = (z - 4) * 64 + blockIdx.y * 8 + blockIdx.x;   // 0..1023
        const int g = (b & 7) * 128 + (b >> 3);
        const int t = g * 2048 + threadIdx.x * 8;
        const int row = t >> 8;
        const int c8  = t & 255;
        f32x8 v = *(const f32x8*)(p.emb + (long)p.tok[row] * 256 + c8);
        u16x8 o;
#pragma unroll
        for (int j = 0; j < 8; ++j) o[j] = f2bf(v[j]);
        *(u16x8*)(p.embB + (long)row * 256 + c8) = o;
    }
}

struct GArgs {
    const u16* A; const u16* B; const float* bias; void* C;
    float* Cpart;
    float* lsum;                          // [16][8192] QK row partial sums
    u16 *qd, *kd, *vTd;
    const float *bq, *bk, *bv;
    int K, lda, ldb, ldc;
    long strA, strB, strC;
    float scale;
};

// MFMA GEMM, dbuf async staging. BM=TM*32, BN=NT*32, BK=32*KSUB. 4 waves 2x2.
// KSUB: BK=32 slabs staged per barrier (LDS [KSUB][rows][32]).
// OCC: __launch_bounds__ min waves/EU.
// EPI: 0 scale, 1 +bias, 2 +bias+GELU.
// CMODE: 0 bf16 C, 1 f32 C, 2 QKV-fused (n0<1024: q/k row-major; n0>=1024:
//        v repacked via LDS [BN][BM+8] -> vT[batch][h][pos]), 3 QK+exp with
//        LDS row-half repack (full-line sc writes) + lsum partials,
//        4 f32 C normalized by 1/l (epilogue smem reuse).
// MX: m-tile fastest. SPLITK: z=batch*2+kh, K half = 1024. XSW: XCD m-stripes.
template <int TM, int NT, int KSUB, int OCC, int EPI, int CMODE,
          bool MX, bool SPLITK, bool XSW>
__launch_bounds__(256, OCC)
__global__ void gemm128(GArgs g)
{
    constexpr int BM  = TM * 32;
    constexpr int BN  = NT * 32;
    constexpr int ASZ = BM * 32;          // one BK=32 slab
    constexpr int BSZ = BN * 32;
    constexpr int BK  = 32 * KSUB;
    __shared__ u16 smem[2 * KSUB * (ASZ + BSZ)];
    u16* As = smem;
    u16* Bs = smem + 2 * KSUB * ASZ;

    const int bz    = blockIdx.z;
    const int batch = SPLITK ? (bz >> 1) : bz;
    const int kh    = SPLITK ? (bz & 1) : 0;
    const u16* A = g.A + g.strA * batch + (SPLITK ? kh * 1024 : 0);
    const u16* B = g.B + g.strB * batch + (SPLITK ? kh * 1024 : 0);

    int m0, n0;
    if (XSW) {
        const int lid = blockIdx.y * gridDim.x + blockIdx.x;
        const int xcd = lid & 7;
        const int j   = lid >> 3;
        const int mper = gridDim.y >> 3;
        m0 = (xcd * mper + (j % mper)) * BM;
        n0 = (j / mper) * BN;
    } else {
        m0 = (MX ? blockIdx.x : blockIdx.y) * BM;
        n0 = (MX ? blockIdx.y : blockIdx.x) * BN;
    }

    const int t = threadIdx.x;
    const int w = t >> 6;
    const int lane = t & 63;
    const int quad = lane >> 4;
    const int l16  = lane & 15;
    const int wm = w >> 1, wn = w & 1;

    const int srow = w * 16 + (lane >> 2);
    const int skc  = (lane & 3) * 8;
    const u16* ga = A + (long)(m0 + srow) * g.lda + skc;
    const u16* gb = B + (long)(n0 + srow) * g.ldb + skc;
    const long a64 = (long)64 * g.lda;
    const long b64 = (long)64 * g.ldb;

    auto stage = [&](int buf, int k0) {
#pragma unroll
        for (int s = 0; s < KSUB; ++s) {
            u16* la = As + (buf * KSUB + s) * ASZ + w * 512;
            u16* lb = Bs + (buf * KSUB + s) * BSZ + w * 512;
#pragma unroll
            for (int i = 0; i < TM / 2; ++i)
                gload_lds16(ga + i * a64 + k0 + s * 32, la + i * 2048);
#pragma unroll
            for (int i = 0; i < NT / 2; ++i)
                gload_lds16(gb + i * b64 + k0 + s * 32, lb + i * 2048);
        }
    };

    f32x4 acc[TM][NT] = {};
    const int K = SPLITK ? 1024 : g.K;

    stage(0, 0);
    int cur = 0;
    for (int k0 = 0; k0 < K; k0 += BK) {
        __syncthreads();
        if (k0 + BK < K) stage(cur ^ 1, k0 + BK);

#pragma unroll
        for (int s = 0; s < KSUB; ++s) {
            const u16* as = As + (cur * KSUB + s) * ASZ;
            const u16* bs = Bs + (cur * KSUB + s) * BSZ;
            s16x8 af[TM], bf[NT];
#pragma unroll
            for (int x = 0; x < TM; ++x)
                af[x] = *(const s16x8*)&as[(wm * (TM * 16) + x * 16 + l16) * 32 + quad * 8];
#pragma unroll
            for (int y = 0; y < NT; ++y)
                bf[y] = *(const s16x8*)&bs[(wn * (NT * 16) + y * 16 + l16) * 32 + quad * 8];
#pragma unroll
            for (int x = 0; x < TM; ++x)
#pragma unroll
                for (int y = 0; y < NT; ++y)
                    acc[x][y] = __builtin_amdgcn_mfma_f32_16x16x32_bf16(af[x], bf[y], acc[x][y], 0, 0, 0);
        }
        cur ^= 1;
    }

    // ---- v-block epilogue (QKV fused, n0 >= 1024): LDS repack -> vT ----
    if constexpr (CMODE == 2) {
        if (n0 >= 1024) {
            constexpr int TPAD = BM + 8;      // padded rows per column
            constexpr int TPC  = BM / 8;      // threads per column (8 u16 each)
            constexpr int CPI  = 256 / TPC;   // columns per write iter
            static_assert(BN * TPAD <= 2 * KSUB * (ASZ + BSZ), "T fits smem");
            u16* T = smem;                    // [BN][TPAD] u16
            __syncthreads();                  // all waves done reading As/Bs
#pragma unroll
            for (int y = 0; y < NT; ++y) {
                const int crel = wn * (NT * 16) + y * 16 + l16;
                const float bval = g.bv[n0 - 1024 + crel];
#pragma unroll
                for (int x = 0; x < TM; ++x)
#pragma unroll
                    for (int r = 0; r < 4; ++r) {
                        const int rrel = wm * (TM * 16) + x * 16 + quad * 4 + r;
                        T[crel * TPAD + rrel] = f2bf(acc[x][y][r] + bval);
                    }
            }
            __syncthreads();
            const int vb  = m0 >> 11;         // batch (BM divides 2048)
            const int pos = m0 & 2047;
            u16* dst = g.vTd + (long)vb * (512l * 2048) + (long)(n0 - 1024) * 2048 + pos;
#pragma unroll
            for (int i = 0; i < BN / CPI; ++i) {
                const int c  = i * CPI + (t / TPC);
                const int ms = (t % TPC) * 8;
                *(u16x8*)(dst + (long)c * 2048 + ms) = *(const u16x8*)&T[c * TPAD + ms];
            }
            return;
        }
    }

    // ---- QK+exp epilogue: LDS row-half repack -> full-line sc writes ----
    if constexpr (CMODE == 3) {
        constexpr int HR   = TM * 16;         // rows per half (wm split)
        constexpr int TPAD = BN + 8;
        constexpr int RPI  = 2048 / BN;       // rows per write iter
        constexpr int TPR  = BN / 8;          // threads per row
        static_assert(HR * TPAD <= 2 * KSUB * (ASZ + BSZ), "T fits smem");
        u16* T = smem;                        // [HR][TPAD] u16
        u16* dstC = (u16*)g.C + g.strC * batch;
        float rs[TM][4];
#pragma unroll
        for (int x = 0; x < TM; ++x)
#pragma unroll
            for (int r = 0; r < 4; ++r) rs[x][r] = 0.0f;

#pragma unroll
        for (int h = 0; h < 2; ++h) {
            __syncthreads();                  // As/Bs reads done / prev half flushed
            if (wm == h) {
#pragma unroll
                for (int y = 0; y < NT; ++y) {
                    const int col = wn * (NT * 16) + y * 16 + l16;
#pragma unroll
                    for (int x = 0; x < TM; ++x)
#pragma unroll
                        for (int r = 0; r < 4; ++r) {
                            const float e = __expf(acc[x][y][r] * g.scale);
                            rs[x][r] += e;
                            T[(x * 16 + quad * 4 + r) * TPAD + col] = f2bf(e);
                        }
                }
            }
            __syncthreads();
#pragma unroll
            for (int i = 0; i < HR / RPI; ++i) {
                const int r_ = i * RPI + t / TPR;
                const int c_ = (t % TPR) * 8;
                *(u16x8*)(dstC + (long)(m0 + h * HR + r_) * g.ldc + n0 + c_) =
                    *(const u16x8*)&T[r_ * TPAD + c_];
            }
        }

#pragma unroll
        for (int x = 0; x < TM; ++x) {
#pragma unroll
            for (int r = 0; r < 4; ++r) {
                float s = rs[x][r];
                s += __shfl_xor(s, 1, 64);
                s += __shfl_xor(s, 2, 64);
                s += __shfl_xor(s, 4, 64);
                s += __shfl_xor(s, 8, 64);
                if (l16 == 0) {
                    const int row = m0 + wm * (TM * 16) + x * 16 + quad * 4 + r;
                    g.lsum[(long)(2 * blockIdx.x + wn) * 8192 + batch * 2048 + row] = s;
                }
            }
        }
        return;
    }

    // CMODE 4: compute 1/l into smem (reused; K-loop done) before the C-write.
    float* invp = (float*)smem;
    if constexpr (CMODE == 4) {
        __syncthreads();                  // all waves done reading As/Bs
        if (t < BM) {
            float l = 0.0f;
#pragma unroll
            for (int j = 0; j < 16; ++j)
                l += g.lsum[(long)j * 8192 + batch * 2048 + m0 + t];
            invp[t] = 1.0f / l;
        }
        __syncthreads();
    }

#pragma unroll
    for (int y = 0; y < NT; ++y) {
        const int col = n0 + wn * (NT * 16) + y * 16 + l16;
        float bval = 0.0f;
        if (CMODE == 2)
            bval = col < 512 ? g.bq[col] : g.bk[col - 512];
        else if (EPI >= 1)
            bval = g.bias[col];
#pragma unroll
        for (int x = 0; x < TM; ++x) {
#pragma unroll
            for (int r = 0; r < 4; ++r) {
                const int row = m0 + wm * (TM * 16) + x * 16 + quad * 4 + r;
                float v = acc[x][y][r] * g.scale + bval;
                if (EPI == 2) v = 0.5f * v * (1.0f + erff(v * 0.70710678118654752f));
                if (CMODE == 2) {
                    u16* dst = col < 512 ? g.qd : g.kd;
                    dst[(long)row * 512 + (col & 511)] = f2bf(v);
                } else if (CMODE == 4) {
                    ((float*)g.C + g.strC * batch)[(long)row * g.ldc + col] = v * invp[row - m0];
                } else if (SPLITK) {
                    float* dst = kh ? g.Cpart : (float*)g.C;
                    dst[g.strC * batch + (long)row * g.ldc + col] = v;
                } else if (CMODE == 1) {
                    ((float*)g.C + g.strC * batch)[(long)row * g.ldc + col] = v;
                } else {
                    ((u16*)g.C + g.strC * batch)[(long)row * g.ldc + col] = f2bf(v);
                }
            }
        }
    }
}

extern "C" void kernel_launch(void* const* d_in, const int* in_sizes, int n_in,
                              void* d_out, int out_size, void* d_ws, size_t ws_size,
                              hipStream_t stream)
{
    const int*   tok = (const int*)d_in[0];
    const float* emb = (const float*)d_in[1];
    const float* W1  = (const float*)d_in[2];
    const float* b1  = (const float*)d_in[3];
    const float* Wq  = (const float*)d_in[4];
    const float* bq  = (const float*)d_in[5];
    const float* Wk  = (const float*)d_in[6];
    const float* bk  = (const float*)d_in[7];
    const float* Wv  = (const float*)d_in[8];
    const float* bv  = (const float*)d_in[9];
    float* out = (float*)d_out;

    u16* act   = (u16*)d_out;                  // [8192][512] bf16 (8 MiB)
    u16* wbase = act + 8192l * 512;
    u16* W1T = wbase;                          // [512][256]
    u16* WqT = wbase + 131072;                 // [1536][512] contiguous
    u16* WkT = WqT + 262144;
    u16* WvT = WkT + 262144;

    char* ws = (char*)d_ws;
    u16* q     = (u16*)(ws);
    u16* k     = (u16*)(ws + (8l  << 20));
    u16* vT    = (u16*)(ws + (16l << 20));     // [4][512][2048]
    u16* sc    = (u16*)(ws + (24l << 20));     // 32 MiB (e values)
    float* lsum = (float*)(ws + (56l << 20));  // [16][8192] f32
    u16* embB  = sc;                           // dead before sc written

    const dim3 blk(256);
    const float iscl = 0.044194173824159216f;  // 1/sqrt(512)
    const long  TB = 2048l * 512;
    const long  SS = 2048l * 2048;

    // 0. prep: weight transposes (z<4) + XCD-striped gather+cvt (z>=4)
    PArgs p;
    p.wsrc[0] = W1; p.wsrc[1] = Wq; p.wsrc[2] = Wk; p.wsrc[3] = Wv;
    p.wdst[0] = W1T; p.wdst[1] = WqT; p.wdst[2] = WkT; p.wdst[3] = WvT;
    p.wK[0] = 256; p.wK[1] = 512; p.wK[2] = 512; p.wK[3] = 512;
    p.emb = emb; p.tok = tok; p.embB = embB;
    prep_k<<<dim3(8, 8, 20), blk, 0, stream>>>(p);

    // 1. act = gelu(embB @ W1T + b1)   M=8192 N=512 K=256  TM=2 NT=4 KSUB=2
    {
        GArgs a = {};
        a.A = embB; a.B = W1T; a.bias = b1; a.C = act;
        a.K = 256; a.lda = 256; a.ldb = 256; a.ldc = 512; a.scale = 1.0f;
        gemm128<2, 4, 2, 2, 2, 0, false, false, true><<<dim3(4, 128, 1), blk, 0, stream>>>(a);
    }
    // 2. fused QKV   M=8192 N=1536 K=512  TM=4 NT=4 KSUB=2 (BM=BN=128, BK=64)
    //    grid (12,64) XSW = 768 blocks, LDS 64KiB -> 2/CU, 32 MFMA/barrier.
    {
        GArgs a = {};
        a.A = act; a.B = WqT; a.K = 512; a.lda = 512; a.ldb = 512; a.scale = 1.0f;
        a.qd = q; a.kd = k; a.vTd = vT; a.bq = bq; a.bk = bk; a.bv = bv;
        gemm128<4, 4, 2, 2, 0, 2, false, false, true><<<dim3(12, 64, 1), blk, 0, stream>>>(a);
    }
    // 3. e = exp(q @ k^T / sqrt(512)) + row sums   M=N=2048 K=512  TM=4 BN=256
    //    sc written via LDS row-half repack (full 512-B row runs).
    {
        GArgs a = {};
        a.A = q; a.B = k; a.C = sc; a.lsum = lsum;
        a.K = 512; a.lda = 512; a.ldb = 512; a.ldc = 2048;
        a.strA = TB; a.strB = TB; a.strC = SS; a.scale = iscl;
        gemm128<4, 8, 1, 2, 0, 3, false, false, false><<<dim3(8, 16, 4), blk, 0, stream>>>(a);
    }
    // 4. out = (e @ vT^T) / l_row   M=2048 N=512 K=2048  TM=2 NT=4 KSUB=2
    //    512 blocks, BK=64: 16 MFMA/barrier; normalize via epilogue smem 1/l.
    {
        GArgs a = {};
        a.A = sc; a.B = vT; a.C = out; a.lsum = lsum;
        a.K = 2048; a.lda = 2048; a.ldb = 2048; a.ldc = 512;
        a.strA = SS; a.strB = TB; a.strC = TB; a.scale = 1.0f;
        gemm128<2, 4, 2, 2, 0, 4, true, false, false><<<dim3(32, 4, 4), blk, 0, stream>>>(a);
    }
}

// Round 15
// 186.349 us; speedup vs baseline: 1.0156x; 1.0156x over previous
//
#include <hip/hip_runtime.h>
#include <math.h>

// ToyModel: B=4, S=2048, E=256, H=512, VOCAB=50257.
// Inputs/output f32; intermediates bf16; MFMA bf16 w/ f32 accum. posneg == identity.
//
// Round 22 resubmit (infra failure last round; kernel never ran).
// r21's failure: CMODE=3 wrote lsum[2*blockIdx.x+wn], valid only when
// blockIdx.x == n-tile index; under XSW two n-tiles can share blockIdx.x ->
// slot collision -> dropped exp-sum slice (absmax 0.4). Now the slot is
// 2*(n0/BN)+wn — identical to the old expression without XSW (strict
// generalization), correct with it.
// Experiment: stage 3 (QK, ~3.8TB/s, HBM-bound) gets T1 XCD swizzle; grid
// (8,16,4) bijective under XSW (mper=2): each XCD owns 2 m-stripes x all 8
// n-tiles -> its q (256KB) + k (2MB/batch) L2-resident.
// Rest = r19 (186.8us best): s2 TM=4 NT=4 KSUB=2, s1/s4 KSUB=2, CMODE=4
// epilogue-smem normalizer.
//
// ws: q@0 | k@8MiB | vT@16MiB | sc@24MiB(32MiB) | lsum@56MiB(512KB).
// embB aliases sc (dead before sc written).

typedef unsigned short u16;
typedef u16   u16x8 __attribute__((ext_vector_type(8)));
typedef short s16x8 __attribute__((ext_vector_type(8)));
typedef float f32x4 __attribute__((ext_vector_type(4)));
typedef float f32x8 __attribute__((ext_vector_type(8)));

static __device__ __forceinline__ u16 f2bf(float f) {
    unsigned u = __builtin_bit_cast(unsigned, f);
    u = (u + 0x7fffu + ((u >> 16) & 1u)) >> 16;   // RNE
    return (u16)u;
}

static __device__ __forceinline__ void gload_lds16(const u16* g, u16* l) {
    __builtin_amdgcn_global_load_lds(
        (const __attribute__((address_space(1))) void*)g,
        (__attribute__((address_space(3))) void*)l, 16, 0, 0);
}

struct PArgs {
    const float* wsrc[4];
    u16*         wdst[4];
    int          wK[4];
    const float* emb;
    const int*   tok;
    u16*         embB;
};

// z<4: f32 W[K][512] -> bf16 WT[512][K]. z>=4: XCD-striped gather+cvt of emb rows.
__launch_bounds__(256)
__global__ void prep_k(PArgs p)
{
    const int z = blockIdx.z;
    if (z < 4) {
        const float* W = p.wsrc[z];
        u16* WT = p.wdst[z];
        const int K = p.wK[z];
        const int c0 = blockIdx.x * 64;
        const int r0 = blockIdx.y * 64;
        if (r0 >= K) return;
        __shared__ float T[64][65];
        const int t = threadIdx.x;
        const int col = t & 63;
        const int rb  = t >> 6;
#pragma unroll
        for (int i = 0; i < 16; ++i)
            T[i * 4 + rb][col] = W[(long)(r0 + i * 4 + rb) * 512 + c0 + col];
        __syncthreads();
#pragma unroll
        for (int i = 0; i < 16; ++i) {
            const int orow = i * 4 + rb;
            WT[(long)(c0 + orow) * K + r0 + col] = f2bf(T[col][orow]);
        }
    } else {
        const int b = (z - 4) * 64 + blockIdx.y * 8 + blockIdx.x;   // 0..1023
        const int g = (b & 7) * 128 + (b >> 3);
        const int t = g * 2048 + threadIdx.x * 8;
        const int row = t >> 8;
        const int c8  = t & 255;
        f32x8 v = *(const f32x8*)(p.emb + (long)p.tok[row] * 256 + c8);
        u16x8 o;
#pragma unroll
        for (int j = 0; j < 8; ++j) o[j] = f2bf(v[j]);
        *(u16x8*)(p.embB + (long)row * 256 + c8) = o;
    }
}

struct GArgs {
    const u16* A; const u16* B; const float* bias; void* C;
    float* Cpart;
    float* lsum;                          // [16][8192] QK row partial sums
    u16 *qd, *kd, *vTd;
    const float *bq, *bk, *bv;
    int K, lda, ldb, ldc;
    long strA, strB, strC;
    float scale;
};

// MFMA GEMM, dbuf async staging. BM=TM*32, BN=NT*32, BK=32*KSUB. 4 waves 2x2.
// KSUB: BK=32 slabs staged per barrier (LDS [KSUB][rows][32]).
// OCC: __launch_bounds__ min waves/EU.
// EPI: 0 scale, 1 +bias, 2 +bias+GELU.
// CMODE: 0 bf16 C, 1 f32 C, 2 QKV-fused (n0<1024: q/k row-major; n0>=1024:
//        v repacked via LDS [BN][BM+8] -> vT[batch][h][pos]), 3 QK+exp
//        (lsum slot = 2*(n0/BN)+wn, XSW-safe), 4 f32 C normalized by 1/l
//        (epilogue smem reuse).
// MX: m-tile fastest. SPLITK: z=batch*2+kh, K half = 1024. XSW: XCD m-stripes.
template <int TM, int NT, int KSUB, int OCC, int EPI, int CMODE,
          bool MX, bool SPLITK, bool XSW>
__launch_bounds__(256, OCC)
__global__ void gemm128(GArgs g)
{
    constexpr int BM  = TM * 32;
    constexpr int BN  = NT * 32;
    constexpr int ASZ = BM * 32;          // one BK=32 slab
    constexpr int BSZ = BN * 32;
    constexpr int BK  = 32 * KSUB;
    __shared__ u16 smem[2 * KSUB * (ASZ + BSZ)];
    u16* As = smem;
    u16* Bs = smem + 2 * KSUB * ASZ;

    const int bz    = blockIdx.z;
    const int batch = SPLITK ? (bz >> 1) : bz;
    const int kh    = SPLITK ? (bz & 1) : 0;
    const u16* A = g.A + g.strA * batch + (SPLITK ? kh * 1024 : 0);
    const u16* B = g.B + g.strB * batch + (SPLITK ? kh * 1024 : 0);

    int m0, n0;
    if (XSW) {
        const int lid = blockIdx.y * gridDim.x + blockIdx.x;
        const int xcd = lid & 7;
        const int j   = lid >> 3;
        const int mper = gridDim.y >> 3;
        m0 = (xcd * mper + (j % mper)) * BM;
        n0 = (j / mper) * BN;
    } else {
        m0 = (MX ? blockIdx.x : blockIdx.y) * BM;
        n0 = (MX ? blockIdx.y : blockIdx.x) * BN;
    }

    const int t = threadIdx.x;
    const int w = t >> 6;
    const int lane = t & 63;
    const int quad = lane >> 4;
    const int l16  = lane & 15;
    const int wm = w >> 1, wn = w & 1;

    const int srow = w * 16 + (lane >> 2);
    const int skc  = (lane & 3) * 8;
    const u16* ga = A + (long)(m0 + srow) * g.lda + skc;
    const u16* gb = B + (long)(n0 + srow) * g.ldb + skc;
    const long a64 = (long)64 * g.lda;
    const long b64 = (long)64 * g.ldb;

    auto stage = [&](int buf, int k0) {
#pragma unroll
        for (int s = 0; s < KSUB; ++s) {
            u16* la = As + (buf * KSUB + s) * ASZ + w * 512;
            u16* lb = Bs + (buf * KSUB + s) * BSZ + w * 512;
#pragma unroll
            for (int i = 0; i < TM / 2; ++i)
                gload_lds16(ga + i * a64 + k0 + s * 32, la + i * 2048);
#pragma unroll
            for (int i = 0; i < NT / 2; ++i)
                gload_lds16(gb + i * b64 + k0 + s * 32, lb + i * 2048);
        }
    };

    f32x4 acc[TM][NT] = {};
    const int K = SPLITK ? 1024 : g.K;

    stage(0, 0);
    int cur = 0;
    for (int k0 = 0; k0 < K; k0 += BK) {
        __syncthreads();
        if (k0 + BK < K) stage(cur ^ 1, k0 + BK);

#pragma unroll
        for (int s = 0; s < KSUB; ++s) {
            const u16* as = As + (cur * KSUB + s) * ASZ;
            const u16* bs = Bs + (cur * KSUB + s) * BSZ;
            s16x8 af[TM], bf[NT];
#pragma unroll
            for (int x = 0; x < TM; ++x)
                af[x] = *(const s16x8*)&as[(wm * (TM * 16) + x * 16 + l16) * 32 + quad * 8];
#pragma unroll
            for (int y = 0; y < NT; ++y)
                bf[y] = *(const s16x8*)&bs[(wn * (NT * 16) + y * 16 + l16) * 32 + quad * 8];
#pragma unroll
            for (int x = 0; x < TM; ++x)
#pragma unroll
                for (int y = 0; y < NT; ++y)
                    acc[x][y] = __builtin_amdgcn_mfma_f32_16x16x32_bf16(af[x], bf[y], acc[x][y], 0, 0, 0);
        }
        cur ^= 1;
    }

    // ---- v-block epilogue (QKV fused, n0 >= 1024): LDS repack -> vT ----
    if constexpr (CMODE == 2) {
        if (n0 >= 1024) {
            constexpr int TPAD = BM + 8;      // padded rows per column
            constexpr int TPC  = BM / 8;      // threads per column (8 u16 each)
            constexpr int CPI  = 256 / TPC;   // columns per write iter
            static_assert(BN * TPAD <= 2 * KSUB * (ASZ + BSZ), "T fits smem");
            u16* T = smem;                    // [BN][TPAD] u16
            __syncthreads();                  // all waves done reading As/Bs
#pragma unroll
            for (int y = 0; y < NT; ++y) {
                const int crel = wn * (NT * 16) + y * 16 + l16;
                const float bval = g.bv[n0 - 1024 + crel];
#pragma unroll
                for (int x = 0; x < TM; ++x)
#pragma unroll
                    for (int r = 0; r < 4; ++r) {
                        const int rrel = wm * (TM * 16) + x * 16 + quad * 4 + r;
                        T[crel * TPAD + rrel] = f2bf(acc[x][y][r] + bval);
                    }
            }
            __syncthreads();
            const int vb  = m0 >> 11;         // batch (BM divides 2048)
            const int pos = m0 & 2047;
            u16* dst = g.vTd + (long)vb * (512l * 2048) + (long)(n0 - 1024) * 2048 + pos;
#pragma unroll
            for (int i = 0; i < BN / CPI; ++i) {
                const int c  = i * CPI + (t / TPC);
                const int ms = (t % TPC) * 8;
                *(u16x8*)(dst + (long)c * 2048 + ms) = *(const u16x8*)&T[c * TPAD + ms];
            }
            return;
        }
    }

    // CMODE 4: compute 1/l into smem (reused; K-loop done) before the C-write.
    float* invp = (float*)smem;
    if constexpr (CMODE == 4) {
        __syncthreads();                  // all waves done reading As/Bs
        if (t < BM) {
            float l = 0.0f;
#pragma unroll
            for (int j = 0; j < 16; ++j)
                l += g.lsum[(long)j * 8192 + batch * 2048 + m0 + t];
            invp[t] = 1.0f / l;
        }
        __syncthreads();
    }

    float rs[TM][4];
    if (CMODE == 3)
#pragma unroll
        for (int x = 0; x < TM; ++x)
#pragma unroll
            for (int r = 0; r < 4; ++r) rs[x][r] = 0.0f;

#pragma unroll
    for (int y = 0; y < NT; ++y) {
        const int col = n0 + wn * (NT * 16) + y * 16 + l16;
        float bval = 0.0f;
        if (CMODE == 2)
            bval = col < 512 ? g.bq[col] : g.bk[col - 512];
        else if (EPI >= 1)
            bval = g.bias[col];
#pragma unroll
        for (int x = 0; x < TM; ++x) {
#pragma unroll
            for (int r = 0; r < 4; ++r) {
                const int row = m0 + wm * (TM * 16) + x * 16 + quad * 4 + r;
                float v = acc[x][y][r] * g.scale + bval;
                if (EPI == 2) v = 0.5f * v * (1.0f + erff(v * 0.70710678118654752f));
                if (CMODE == 3) {
                    const float e = __expf(v);
                    rs[x][r] += e;
                    ((u16*)g.C + g.strC * batch)[(long)row * g.ldc + col] = f2bf(e);
                } else if (CMODE == 2) {
                    u16* dst = col < 512 ? g.qd : g.kd;
                    dst[(long)row * 512 + (col & 511)] = f2bf(v);
                } else if (CMODE == 4) {
                    ((float*)g.C + g.strC * batch)[(long)row * g.ldc + col] = v * invp[row - m0];
                } else if (SPLITK) {
                    float* dst = kh ? g.Cpart : (float*)g.C;
                    dst[g.strC * batch + (long)row * g.ldc + col] = v;
                } else if (CMODE == 1) {
                    ((float*)g.C + g.strC * batch)[(long)row * g.ldc + col] = v;
                } else {
                    ((u16*)g.C + g.strC * batch)[(long)row * g.ldc + col] = f2bf(v);
                }
            }
        }
    }

    if (CMODE == 3) {
        const int nslot = 2 * (n0 / BN) + wn;   // logical n-tile slot (XSW-safe)
#pragma unroll
        for (int x = 0; x < TM; ++x) {
#pragma unroll
            for (int r = 0; r < 4; ++r) {
                float s = rs[x][r];
                s += __shfl_xor(s, 1, 64);
                s += __shfl_xor(s, 2, 64);
                s += __shfl_xor(s, 4, 64);
                s += __shfl_xor(s, 8, 64);
                if (l16 == 0) {
                    const int row = m0 + wm * (TM * 16) + x * 16 + quad * 4 + r;
                    g.lsum[(long)nslot * 8192 + batch * 2048 + row] = s;
                }
            }
        }
    }
}

extern "C" void kernel_launch(void* const* d_in, const int* in_sizes, int n_in,
                              void* d_out, int out_size, void* d_ws, size_t ws_size,
                              hipStream_t stream)
{
    const int*   tok = (const int*)d_in[0];
    const float* emb = (const float*)d_in[1];
    const float* W1  = (const float*)d_in[2];
    const float* b1  = (const float*)d_in[3];
    const float* Wq  = (const float*)d_in[4];
    const float* bq  = (const float*)d_in[5];
    const float* Wk  = (const float*)d_in[6];
    const float* bk  = (const float*)d_in[7];
    const float* Wv  = (const float*)d_in[8];
    const float* bv  = (const float*)d_in[9];
    float* out = (float*)d_out;

    u16* act   = (u16*)d_out;                  // [8192][512] bf16 (8 MiB)
    u16* wbase = act + 8192l * 512;
    u16* W1T = wbase;                          // [512][256]
    u16* WqT = wbase + 131072;                 // [1536][512] contiguous
    u16* WkT = WqT + 262144;
    u16* WvT = WkT + 262144;

    char* ws = (char*)d_ws;
    u16* q     = (u16*)(ws);
    u16* k     = (u16*)(ws + (8l  << 20));
    u16* vT    = (u16*)(ws + (16l << 20));     // [4][512][2048]
    u16* sc    = (u16*)(ws + (24l << 20));     // 32 MiB (e values)
    float* lsum = (float*)(ws + (56l << 20));  // [16][8192] f32
    u16* embB  = sc;                           // dead before sc written

    const dim3 blk(256);
    const float iscl = 0.044194173824159216f;  // 1/sqrt(512)
    const long  TB = 2048l * 512;
    const long  SS = 2048l * 2048;

    // 0. prep: weight transposes (z<4) + XCD-striped gather+cvt (z>=4)
    PArgs p;
    p.wsrc[0] = W1; p.wsrc[1] = Wq; p.wsrc[2] = Wk; p.wsrc[3] = Wv;
    p.wdst[0] = W1T; p.wdst[1] = WqT; p.wdst[2] = WkT; p.wdst[3] = WvT;
    p.wK[0] = 256; p.wK[1] = 512; p.wK[2] = 512; p.wK[3] = 512;
    p.emb = emb; p.tok = tok; p.embB = embB;
    prep_k<<<dim3(8, 8, 20), blk, 0, stream>>>(p);

    // 1. act = gelu(embB @ W1T + b1)   M=8192 N=512 K=256  TM=2 NT=4 KSUB=2
    {
        GArgs a = {};
        a.A = embB; a.B = W1T; a.bias = b1; a.C = act;
        a.K = 256; a.lda = 256; a.ldb = 256; a.ldc = 512; a.scale = 1.0f;
        gemm128<2, 4, 2, 2, 2, 0, false, false, true><<<dim3(4, 128, 1), blk, 0, stream>>>(a);
    }
    // 2. fused QKV   M=8192 N=1536 K=512  TM=4 NT=4 KSUB=2 (BM=BN=128, BK=64)
    //    grid (12,64) XSW = 768 blocks, LDS 64KiB -> 2/CU, 32 MFMA/barrier.
    {
        GArgs a = {};
        a.A = act; a.B = WqT; a.K = 512; a.lda = 512; a.ldb = 512; a.scale = 1.0f;
        a.qd = q; a.kd = k; a.vTd = vT; a.bq = bq; a.bk = bk; a.bv = bv;
        gemm128<4, 4, 2, 2, 0, 2, false, false, true><<<dim3(12, 64, 1), blk, 0, stream>>>(a);
    }
    // 3. e = exp(q @ k^T / sqrt(512)) + row sums   M=N=2048 K=512  TM=4 BN=256
    //    XSW (T1): grid (8,16,4), mper=2 — each XCD owns 2 m-stripes x all n.
    //    lsum slot 2*(n0/BN)+wn (XSW-safe).
    {
        GArgs a = {};
        a.A = q; a.B = k; a.C = sc; a.lsum = lsum;
        a.K = 512; a.lda = 512; a.ldb = 512; a.ldc = 2048;
        a.strA = TB; a.strB = TB; a.strC = SS; a.scale = iscl;
        gemm128<4, 8, 1, 2, 0, 3, false, false, true><<<dim3(8, 16, 4), blk, 0, stream>>>(a);
    }
    // 4. out = (e @ vT^T) / l_row   M=2048 N=512 K=2048  TM=2 NT=4 KSUB=2
    //    512 blocks, BK=64: 16 MFMA/barrier; normalize via epilogue smem 1/l.
    {
        GArgs a = {};
        a.A = sc; a.B = vT; a.C = out; a.lsum = lsum;
        a.K = 2048; a.lda = 2048; a.ldb = 2048; a.ldc = 512;
        a.strA = SS; a.strB = TB; a.strC = TB; a.scale = 1.0f;
        gemm128<2, 4, 2, 2, 0, 4, true, false, false><<<dim3(32, 4, 4), blk, 0, stream>>>(a);
    }
}

// Round 16
// 185.446 us; speedup vs baseline: 1.0205x; 1.0049x over previous
//
#include <hip/hip_runtime.h>
#include <math.h>

// ToyModel: B=4, S=2048, E=256, H=512, VOCAB=50257.
// Inputs/output f32; intermediates bf16; MFMA bf16 w/ f32 accum. posneg == identity.
//
// Round 23: final safe lever — T1 XCD swizzle on stage 4 (PV). MX-linear
// order scattered same-vT-panel blocks (same n0/batch, walking m) across
// XCDs; XSW groups 4 of them per XCD stripe so each 512KB vT panel is
// pulled once per XCD. Grid reoriented (4,32,4): mper=4, bijective
// (xcd*4+j%4 -> 32 m-tiles, j/4 -> 4 n-tiles). CMODE=4 path is remap-safe
// (uses only m0/n0/batch; lsum read is m0-indexed). Rest = r22 best
// (186.3us): s2 TM=4 NT=4 KSUB=2, s3 XSW + XSW-safe lsum slot, s1/s4
// KSUB=2, CMODE=4 epilogue-smem normalizer.
//
// Ledger (this session): KSUB wins 3x (-8.8, -6.1 total); tile-shrink loss;
// LDS read-swizzle null; PIPE counted-vmcnt null on this template; QK
// write-repack loss; QK XCD-swizzle null. Remaining headroom = 8-phase
// structural rewrite (out of scope).
//
// ws: q@0 | k@8MiB | vT@16MiB | sc@24MiB(32MiB) | lsum@56MiB(512KB).
// embB aliases sc (dead before sc written).

typedef unsigned short u16;
typedef u16   u16x8 __attribute__((ext_vector_type(8)));
typedef short s16x8 __attribute__((ext_vector_type(8)));
typedef float f32x4 __attribute__((ext_vector_type(4)));
typedef float f32x8 __attribute__((ext_vector_type(8)));

static __device__ __forceinline__ u16 f2bf(float f) {
    unsigned u = __builtin_bit_cast(unsigned, f);
    u = (u + 0x7fffu + ((u >> 16) & 1u)) >> 16;   // RNE
    return (u16)u;
}

static __device__ __forceinline__ void gload_lds16(const u16* g, u16* l) {
    __builtin_amdgcn_global_load_lds(
        (const __attribute__((address_space(1))) void*)g,
        (__attribute__((address_space(3))) void*)l, 16, 0, 0);
}

struct PArgs {
    const float* wsrc[4];
    u16*         wdst[4];
    int          wK[4];
    const float* emb;
    const int*   tok;
    u16*         embB;
};

// z<4: f32 W[K][512] -> bf16 WT[512][K]. z>=4: XCD-striped gather+cvt of emb rows.
__launch_bounds__(256)
__global__ void prep_k(PArgs p)
{
    const int z = blockIdx.z;
    if (z < 4) {
        const float* W = p.wsrc[z];
        u16* WT = p.wdst[z];
        const int K = p.wK[z];
        const int c0 = blockIdx.x * 64;
        const int r0 = blockIdx.y * 64;
        if (r0 >= K) return;
        __shared__ float T[64][65];
        const int t = threadIdx.x;
        const int col = t & 63;
        const int rb  = t >> 6;
#pragma unroll
        for (int i = 0; i < 16; ++i)
            T[i * 4 + rb][col] = W[(long)(r0 + i * 4 + rb) * 512 + c0 + col];
        __syncthreads();
#pragma unroll
        for (int i = 0; i < 16; ++i) {
            const int orow = i * 4 + rb;
            WT[(long)(c0 + orow) * K + r0 + col] = f2bf(T[col][orow]);
        }
    } else {
        const int b = (z - 4) * 64 + blockIdx.y * 8 + blockIdx.x;   // 0..1023
        const int g = (b & 7) * 128 + (b >> 3);
        const int t = g * 2048 + threadIdx.x * 8;
        const int row = t >> 8;
        const int c8  = t & 255;
        f32x8 v = *(const f32x8*)(p.emb + (long)p.tok[row] * 256 + c8);
        u16x8 o;
#pragma unroll
        for (int j = 0; j < 8; ++j) o[j] = f2bf(v[j]);
        *(u16x8*)(p.embB + (long)row * 256 + c8) = o;
    }
}

struct GArgs {
    const u16* A; const u16* B; const float* bias; void* C;
    float* Cpart;
    float* lsum;                          // [16][8192] QK row partial sums
    u16 *qd, *kd, *vTd;
    const float *bq, *bk, *bv;
    int K, lda, ldb, ldc;
    long strA, strB, strC;
    float scale;
};

// MFMA GEMM, dbuf async staging. BM=TM*32, BN=NT*32, BK=32*KSUB. 4 waves 2x2.
// KSUB: BK=32 slabs staged per barrier (LDS [KSUB][rows][32]).
// OCC: __launch_bounds__ min waves/EU.
// EPI: 0 scale, 1 +bias, 2 +bias+GELU.
// CMODE: 0 bf16 C, 1 f32 C, 2 QKV-fused (n0<1024: q/k row-major; n0>=1024:
//        v repacked via LDS [BN][BM+8] -> vT[batch][h][pos]), 3 QK+exp
//        (lsum slot = 2*(n0/BN)+wn, XSW-safe), 4 f32 C normalized by 1/l
//        (epilogue smem reuse).
// MX: m-tile fastest. SPLITK: z=batch*2+kh, K half = 1024. XSW: XCD m-stripes.
template <int TM, int NT, int KSUB, int OCC, int EPI, int CMODE,
          bool MX, bool SPLITK, bool XSW>
__launch_bounds__(256, OCC)
__global__ void gemm128(GArgs g)
{
    constexpr int BM  = TM * 32;
    constexpr int BN  = NT * 32;
    constexpr int ASZ = BM * 32;          // one BK=32 slab
    constexpr int BSZ = BN * 32;
    constexpr int BK  = 32 * KSUB;
    __shared__ u16 smem[2 * KSUB * (ASZ + BSZ)];
    u16* As = smem;
    u16* Bs = smem + 2 * KSUB * ASZ;

    const int bz    = blockIdx.z;
    const int batch = SPLITK ? (bz >> 1) : bz;
    const int kh    = SPLITK ? (bz & 1) : 0;
    const u16* A = g.A + g.strA * batch + (SPLITK ? kh * 1024 : 0);
    const u16* B = g.B + g.strB * batch + (SPLITK ? kh * 1024 : 0);

    int m0, n0;
    if (XSW) {
        const int lid = blockIdx.y * gridDim.x + blockIdx.x;
        const int xcd = lid & 7;
        const int j   = lid >> 3;
        const int mper = gridDim.y >> 3;
        m0 = (xcd * mper + (j % mper)) * BM;
        n0 = (j / mper) * BN;
    } else {
        m0 = (MX ? blockIdx.x : blockIdx.y) * BM;
        n0 = (MX ? blockIdx.y : blockIdx.x) * BN;
    }

    const int t = threadIdx.x;
    const int w = t >> 6;
    const int lane = t & 63;
    const int quad = lane >> 4;
    const int l16  = lane & 15;
    const int wm = w >> 1, wn = w & 1;

    const int srow = w * 16 + (lane >> 2);
    const int skc  = (lane & 3) * 8;
    const u16* ga = A + (long)(m0 + srow) * g.lda + skc;
    const u16* gb = B + (long)(n0 + srow) * g.ldb + skc;
    const long a64 = (long)64 * g.lda;
    const long b64 = (long)64 * g.ldb;

    auto stage = [&](int buf, int k0) {
#pragma unroll
        for (int s = 0; s < KSUB; ++s) {
            u16* la = As + (buf * KSUB + s) * ASZ + w * 512;
            u16* lb = Bs + (buf * KSUB + s) * BSZ + w * 512;
#pragma unroll
            for (int i = 0; i < TM / 2; ++i)
                gload_lds16(ga + i * a64 + k0 + s * 32, la + i * 2048);
#pragma unroll
            for (int i = 0; i < NT / 2; ++i)
                gload_lds16(gb + i * b64 + k0 + s * 32, lb + i * 2048);
        }
    };

    f32x4 acc[TM][NT] = {};
    const int K = SPLITK ? 1024 : g.K;

    stage(0, 0);
    int cur = 0;
    for (int k0 = 0; k0 < K; k0 += BK) {
        __syncthreads();
        if (k0 + BK < K) stage(cur ^ 1, k0 + BK);

#pragma unroll
        for (int s = 0; s < KSUB; ++s) {
            const u16* as = As + (cur * KSUB + s) * ASZ;
            const u16* bs = Bs + (cur * KSUB + s) * BSZ;
            s16x8 af[TM], bf[NT];
#pragma unroll
            for (int x = 0; x < TM; ++x)
                af[x] = *(const s16x8*)&as[(wm * (TM * 16) + x * 16 + l16) * 32 + quad * 8];
#pragma unroll
            for (int y = 0; y < NT; ++y)
                bf[y] = *(const s16x8*)&bs[(wn * (NT * 16) + y * 16 + l16) * 32 + quad * 8];
#pragma unroll
            for (int x = 0; x < TM; ++x)
#pragma unroll
                for (int y = 0; y < NT; ++y)
                    acc[x][y] = __builtin_amdgcn_mfma_f32_16x16x32_bf16(af[x], bf[y], acc[x][y], 0, 0, 0);
        }
        cur ^= 1;
    }

    // ---- v-block epilogue (QKV fused, n0 >= 1024): LDS repack -> vT ----
    if constexpr (CMODE == 2) {
        if (n0 >= 1024) {
            constexpr int TPAD = BM + 8;      // padded rows per column
            constexpr int TPC  = BM / 8;      // threads per column (8 u16 each)
            constexpr int CPI  = 256 / TPC;   // columns per write iter
            static_assert(BN * TPAD <= 2 * KSUB * (ASZ + BSZ), "T fits smem");
            u16* T = smem;                    // [BN][TPAD] u16
            __syncthreads();                  // all waves done reading As/Bs
#pragma unroll
            for (int y = 0; y < NT; ++y) {
                const int crel = wn * (NT * 16) + y * 16 + l16;
                const float bval = g.bv[n0 - 1024 + crel];
#pragma unroll
                for (int x = 0; x < TM; ++x)
#pragma unroll
                    for (int r = 0; r < 4; ++r) {
                        const int rrel = wm * (TM * 16) + x * 16 + quad * 4 + r;
                        T[crel * TPAD + rrel] = f2bf(acc[x][y][r] + bval);
                    }
            }
            __syncthreads();
            const int vb  = m0 >> 11;         // batch (BM divides 2048)
            const int pos = m0 & 2047;
            u16* dst = g.vTd + (long)vb * (512l * 2048) + (long)(n0 - 1024) * 2048 + pos;
#pragma unroll
            for (int i = 0; i < BN / CPI; ++i) {
                const int c  = i * CPI + (t / TPC);
                const int ms = (t % TPC) * 8;
                *(u16x8*)(dst + (long)c * 2048 + ms) = *(const u16x8*)&T[c * TPAD + ms];
            }
            return;
        }
    }

    // CMODE 4: compute 1/l into smem (reused; K-loop done) before the C-write.
    float* invp = (float*)smem;
    if constexpr (CMODE == 4) {
        __syncthreads();                  // all waves done reading As/Bs
        if (t < BM) {
            float l = 0.0f;
#pragma unroll
            for (int j = 0; j < 16; ++j)
                l += g.lsum[(long)j * 8192 + batch * 2048 + m0 + t];
            invp[t] = 1.0f / l;
        }
        __syncthreads();
    }

    float rs[TM][4];
    if (CMODE == 3)
#pragma unroll
        for (int x = 0; x < TM; ++x)
#pragma unroll
            for (int r = 0; r < 4; ++r) rs[x][r] = 0.0f;

#pragma unroll
    for (int y = 0; y < NT; ++y) {
        const int col = n0 + wn * (NT * 16) + y * 16 + l16;
        float bval = 0.0f;
        if (CMODE == 2)
            bval = col < 512 ? g.bq[col] : g.bk[col - 512];
        else if (EPI >= 1)
            bval = g.bias[col];
#pragma unroll
        for (int x = 0; x < TM; ++x) {
#pragma unroll
            for (int r = 0; r < 4; ++r) {
                const int row = m0 + wm * (TM * 16) + x * 16 + quad * 4 + r;
                float v = acc[x][y][r] * g.scale + bval;
                if (EPI == 2) v = 0.5f * v * (1.0f + erff(v * 0.70710678118654752f));
                if (CMODE == 3) {
                    const float e = __expf(v);
                    rs[x][r] += e;
                    ((u16*)g.C + g.strC * batch)[(long)row * g.ldc + col] = f2bf(e);
                } else if (CMODE == 2) {
                    u16* dst = col < 512 ? g.qd : g.kd;
                    dst[(long)row * 512 + (col & 511)] = f2bf(v);
                } else if (CMODE == 4) {
                    ((float*)g.C + g.strC * batch)[(long)row * g.ldc + col] = v * invp[row - m0];
                } else if (SPLITK) {
                    float* dst = kh ? g.Cpart : (float*)g.C;
                    dst[g.strC * batch + (long)row * g.ldc + col] = v;
                } else if (CMODE == 1) {
                    ((float*)g.C + g.strC * batch)[(long)row * g.ldc + col] = v;
                } else {
                    ((u16*)g.C + g.strC * batch)[(long)row * g.ldc + col] = f2bf(v);
                }
            }
        }
    }

    if (CMODE == 3) {
        const int nslot = 2 * (n0 / BN) + wn;   // logical n-tile slot (XSW-safe)
#pragma unroll
        for (int x = 0; x < TM; ++x) {
#pragma unroll
            for (int r = 0; r < 4; ++r) {
                float s = rs[x][r];
                s += __shfl_xor(s, 1, 64);
                s += __shfl_xor(s, 2, 64);
                s += __shfl_xor(s, 4, 64);
                s += __shfl_xor(s, 8, 64);
                if (l16 == 0) {
                    const int row = m0 + wm * (TM * 16) + x * 16 + quad * 4 + r;
                    g.lsum[(long)nslot * 8192 + batch * 2048 + row] = s;
                }
            }
        }
    }
}

extern "C" void kernel_launch(void* const* d_in, const int* in_sizes, int n_in,
                              void* d_out, int out_size, void* d_ws, size_t ws_size,
                              hipStream_t stream)
{
    const int*   tok = (const int*)d_in[0];
    const float* emb = (const float*)d_in[1];
    const float* W1  = (const float*)d_in[2];
    const float* b1  = (const float*)d_in[3];
    const float* Wq  = (const float*)d_in[4];
    const float* bq  = (const float*)d_in[5];
    const float* Wk  = (const float*)d_in[6];
    const float* bk  = (const float*)d_in[7];
    const float* Wv  = (const float*)d_in[8];
    const float* bv  = (const float*)d_in[9];
    float* out = (float*)d_out;

    u16* act   = (u16*)d_out;                  // [8192][512] bf16 (8 MiB)
    u16* wbase = act + 8192l * 512;
    u16* W1T = wbase;                          // [512][256]
    u16* WqT = wbase + 131072;                 // [1536][512] contiguous
    u16* WkT = WqT + 262144;
    u16* WvT = WkT + 262144;

    char* ws = (char*)d_ws;
    u16* q     = (u16*)(ws);
    u16* k     = (u16*)(ws + (8l  << 20));
    u16* vT    = (u16*)(ws + (16l << 20));     // [4][512][2048]
    u16* sc    = (u16*)(ws + (24l << 20));     // 32 MiB (e values)
    float* lsum = (float*)(ws + (56l << 20));  // [16][8192] f32
    u16* embB  = sc;                           // dead before sc written

    const dim3 blk(256);
    const float iscl = 0.044194173824159216f;  // 1/sqrt(512)
    const long  TB = 2048l * 512;
    const long  SS = 2048l * 2048;

    // 0. prep: weight transposes (z<4) + XCD-striped gather+cvt (z>=4)
    PArgs p;
    p.wsrc[0] = W1; p.wsrc[1] = Wq; p.wsrc[2] = Wk; p.wsrc[3] = Wv;
    p.wdst[0] = W1T; p.wdst[1] = WqT; p.wdst[2] = WkT; p.wdst[3] = WvT;
    p.wK[0] = 256; p.wK[1] = 512; p.wK[2] = 512; p.wK[3] = 512;
    p.emb = emb; p.tok = tok; p.embB = embB;
    prep_k<<<dim3(8, 8, 20), blk, 0, stream>>>(p);

    // 1. act = gelu(embB @ W1T + b1)   M=8192 N=512 K=256  TM=2 NT=4 KSUB=2
    {
        GArgs a = {};
        a.A = embB; a.B = W1T; a.bias = b1; a.C = act;
        a.K = 256; a.lda = 256; a.ldb = 256; a.ldc = 512; a.scale = 1.0f;
        gemm128<2, 4, 2, 2, 2, 0, false, false, true><<<dim3(4, 128, 1), blk, 0, stream>>>(a);
    }
    // 2. fused QKV   M=8192 N=1536 K=512  TM=4 NT=4 KSUB=2 (BM=BN=128, BK=64)
    //    grid (12,64) XSW = 768 blocks, LDS 64KiB -> 2/CU, 32 MFMA/barrier.
    {
        GArgs a = {};
        a.A = act; a.B = WqT; a.K = 512; a.lda = 512; a.ldb = 512; a.scale = 1.0f;
        a.qd = q; a.kd = k; a.vTd = vT; a.bq = bq; a.bk = bk; a.bv = bv;
        gemm128<4, 4, 2, 2, 0, 2, false, false, true><<<dim3(12, 64, 1), blk, 0, stream>>>(a);
    }
    // 3. e = exp(q @ k^T / sqrt(512)) + row sums   M=N=2048 K=512  TM=4 BN=256
    //    XSW: grid (8,16,4), mper=2; lsum slot 2*(n0/BN)+wn (XSW-safe).
    {
        GArgs a = {};
        a.A = q; a.B = k; a.C = sc; a.lsum = lsum;
        a.K = 512; a.lda = 512; a.ldb = 512; a.ldc = 2048;
        a.strA = TB; a.strB = TB; a.strC = SS; a.scale = iscl;
        gemm128<4, 8, 1, 2, 0, 3, false, false, true><<<dim3(8, 16, 4), blk, 0, stream>>>(a);
    }
    // 4. out = (e @ vT^T) / l_row   M=2048 N=512 K=2048  TM=2 NT=4 KSUB=2
    //    XSW: grid (4,32,4), mper=4 — 4 same-vT-panel blocks per XCD stripe;
    //    512 blocks 2/CU, BK=64; normalize via epilogue smem 1/l.
    {
        GArgs a = {};
        a.A = sc; a.B = vT; a.C = out; a.lsum = lsum;
        a.K = 2048; a.lda = 2048; a.ldb = 2048; a.ldc = 512;
        a.strA = SS; a.strB = TB; a.strC = TB; a.scale = 1.0f;
        gemm128<2, 4, 2, 2, 0, 4, false, false, true><<<dim3(4, 32, 4), blk, 0, stream>>>(a);
    }
}

// Round 17
// 185.414 us; speedup vs baseline: 1.0207x; 1.0002x over previous
//
#include <hip/hip_runtime.h>
#include <math.h>

// ToyModel: B=4, S=2048, E=256, H=512, VOCAB=50257.
// Inputs/output f32; intermediates bf16; MFMA bf16 w/ f32 accum. posneg == identity.
//
// Round 24: PV tile 64x128 -> 128x128 (TM=4 NT=4 KSUB=4, BK=128). PV is
// staging-BW-bound (~1150cy L2 fill vs ~320cy MFMA per barrier); 128² cuts
// per-CU staged bytes 1.5 -> 1.0 MB (-33%). Only 256 blocks exist -> 1/CU
// (OCC=1), so KSUB=4 (LDS 128KiB static, 64 MFMA/barrier, 16 barriers) costs
// nothing extra. XSW grid (4,16,4) bijective (mper=2). Geometry = stage-2's
// proven TM=4 pattern; CMODE=4 epilogue is BM-generic. Rest = r23 (185.4us):
// s2 128² KSUB=2, s3 XSW + XSW-safe lsum slot, s1 KSUB=2.
//
// Ledger: KSUB/bigger-tile wins 4x; tile-shrink loss; read-swizzle null;
// counted-vmcnt null here; QK write-repack loss; QK XCD-swizzle null;
// PV XCD-swizzle small win.
//
// ws: q@0 | k@8MiB | vT@16MiB | sc@24MiB(32MiB) | lsum@56MiB(512KB).
// embB aliases sc (dead before sc written).

typedef unsigned short u16;
typedef u16   u16x8 __attribute__((ext_vector_type(8)));
typedef short s16x8 __attribute__((ext_vector_type(8)));
typedef float f32x4 __attribute__((ext_vector_type(4)));
typedef float f32x8 __attribute__((ext_vector_type(8)));

static __device__ __forceinline__ u16 f2bf(float f) {
    unsigned u = __builtin_bit_cast(unsigned, f);
    u = (u + 0x7fffu + ((u >> 16) & 1u)) >> 16;   // RNE
    return (u16)u;
}

static __device__ __forceinline__ void gload_lds16(const u16* g, u16* l) {
    __builtin_amdgcn_global_load_lds(
        (const __attribute__((address_space(1))) void*)g,
        (__attribute__((address_space(3))) void*)l, 16, 0, 0);
}

struct PArgs {
    const float* wsrc[4];
    u16*         wdst[4];
    int          wK[4];
    const float* emb;
    const int*   tok;
    u16*         embB;
};

// z<4: f32 W[K][512] -> bf16 WT[512][K]. z>=4: XCD-striped gather+cvt of emb rows.
__launch_bounds__(256)
__global__ void prep_k(PArgs p)
{
    const int z = blockIdx.z;
    if (z < 4) {
        const float* W = p.wsrc[z];
        u16* WT = p.wdst[z];
        const int K = p.wK[z];
        const int c0 = blockIdx.x * 64;
        const int r0 = blockIdx.y * 64;
        if (r0 >= K) return;
        __shared__ float T[64][65];
        const int t = threadIdx.x;
        const int col = t & 63;
        const int rb  = t >> 6;
#pragma unroll
        for (int i = 0; i < 16; ++i)
            T[i * 4 + rb][col] = W[(long)(r0 + i * 4 + rb) * 512 + c0 + col];
        __syncthreads();
#pragma unroll
        for (int i = 0; i < 16; ++i) {
            const int orow = i * 4 + rb;
            WT[(long)(c0 + orow) * K + r0 + col] = f2bf(T[col][orow]);
        }
    } else {
        const int b = (z - 4) * 64 + blockIdx.y * 8 + blockIdx.x;   // 0..1023
        const int g = (b & 7) * 128 + (b >> 3);
        const int t = g * 2048 + threadIdx.x * 8;
        const int row = t >> 8;
        const int c8  = t & 255;
        f32x8 v = *(const f32x8*)(p.emb + (long)p.tok[row] * 256 + c8);
        u16x8 o;
#pragma unroll
        for (int j = 0; j < 8; ++j) o[j] = f2bf(v[j]);
        *(u16x8*)(p.embB + (long)row * 256 + c8) = o;
    }
}

struct GArgs {
    const u16* A; const u16* B; const float* bias; void* C;
    float* Cpart;
    float* lsum;                          // [16][8192] QK row partial sums
    u16 *qd, *kd, *vTd;
    const float *bq, *bk, *bv;
    int K, lda, ldb, ldc;
    long strA, strB, strC;
    float scale;
};

// MFMA GEMM, dbuf async staging. BM=TM*32, BN=NT*32, BK=32*KSUB. 4 waves 2x2.
// KSUB: BK=32 slabs staged per barrier (LDS [KSUB][rows][32]).
// OCC: __launch_bounds__ min waves/EU.
// EPI: 0 scale, 1 +bias, 2 +bias+GELU.
// CMODE: 0 bf16 C, 1 f32 C, 2 QKV-fused (n0<1024: q/k row-major; n0>=1024:
//        v repacked via LDS [BN][BM+8] -> vT[batch][h][pos]), 3 QK+exp
//        (lsum slot = 2*(n0/BN)+wn, XSW-safe), 4 f32 C normalized by 1/l
//        (epilogue smem reuse).
// MX: m-tile fastest. SPLITK: z=batch*2+kh, K half = 1024. XSW: XCD m-stripes.
template <int TM, int NT, int KSUB, int OCC, int EPI, int CMODE,
          bool MX, bool SPLITK, bool XSW>
__launch_bounds__(256, OCC)
__global__ void gemm128(GArgs g)
{
    constexpr int BM  = TM * 32;
    constexpr int BN  = NT * 32;
    constexpr int ASZ = BM * 32;          // one BK=32 slab
    constexpr int BSZ = BN * 32;
    constexpr int BK  = 32 * KSUB;
    __shared__ u16 smem[2 * KSUB * (ASZ + BSZ)];
    u16* As = smem;
    u16* Bs = smem + 2 * KSUB * ASZ;

    const int bz    = blockIdx.z;
    const int batch = SPLITK ? (bz >> 1) : bz;
    const int kh    = SPLITK ? (bz & 1) : 0;
    const u16* A = g.A + g.strA * batch + (SPLITK ? kh * 1024 : 0);
    const u16* B = g.B + g.strB * batch + (SPLITK ? kh * 1024 : 0);

    int m0, n0;
    if (XSW) {
        const int lid = blockIdx.y * gridDim.x + blockIdx.x;
        const int xcd = lid & 7;
        const int j   = lid >> 3;
        const int mper = gridDim.y >> 3;
        m0 = (xcd * mper + (j % mper)) * BM;
        n0 = (j / mper) * BN;
    } else {
        m0 = (MX ? blockIdx.x : blockIdx.y) * BM;
        n0 = (MX ? blockIdx.y : blockIdx.x) * BN;
    }

    const int t = threadIdx.x;
    const int w = t >> 6;
    const int lane = t & 63;
    const int quad = lane >> 4;
    const int l16  = lane & 15;
    const int wm = w >> 1, wn = w & 1;

    const int srow = w * 16 + (lane >> 2);
    const int skc  = (lane & 3) * 8;
    const u16* ga = A + (long)(m0 + srow) * g.lda + skc;
    const u16* gb = B + (long)(n0 + srow) * g.ldb + skc;
    const long a64 = (long)64 * g.lda;
    const long b64 = (long)64 * g.ldb;

    auto stage = [&](int buf, int k0) {
#pragma unroll
        for (int s = 0; s < KSUB; ++s) {
            u16* la = As + (buf * KSUB + s) * ASZ + w * 512;
            u16* lb = Bs + (buf * KSUB + s) * BSZ + w * 512;
#pragma unroll
            for (int i = 0; i < TM / 2; ++i)
                gload_lds16(ga + i * a64 + k0 + s * 32, la + i * 2048);
#pragma unroll
            for (int i = 0; i < NT / 2; ++i)
                gload_lds16(gb + i * b64 + k0 + s * 32, lb + i * 2048);
        }
    };

    f32x4 acc[TM][NT] = {};
    const int K = SPLITK ? 1024 : g.K;

    stage(0, 0);
    int cur = 0;
    for (int k0 = 0; k0 < K; k0 += BK) {
        __syncthreads();
        if (k0 + BK < K) stage(cur ^ 1, k0 + BK);

#pragma unroll
        for (int s = 0; s < KSUB; ++s) {
            const u16* as = As + (cur * KSUB + s) * ASZ;
            const u16* bs = Bs + (cur * KSUB + s) * BSZ;
            s16x8 af[TM], bf[NT];
#pragma unroll
            for (int x = 0; x < TM; ++x)
                af[x] = *(const s16x8*)&as[(wm * (TM * 16) + x * 16 + l16) * 32 + quad * 8];
#pragma unroll
            for (int y = 0; y < NT; ++y)
                bf[y] = *(const s16x8*)&bs[(wn * (NT * 16) + y * 16 + l16) * 32 + quad * 8];
#pragma unroll
            for (int x = 0; x < TM; ++x)
#pragma unroll
                for (int y = 0; y < NT; ++y)
                    acc[x][y] = __builtin_amdgcn_mfma_f32_16x16x32_bf16(af[x], bf[y], acc[x][y], 0, 0, 0);
        }
        cur ^= 1;
    }

    // ---- v-block epilogue (QKV fused, n0 >= 1024): LDS repack -> vT ----
    if constexpr (CMODE == 2) {
        if (n0 >= 1024) {
            constexpr int TPAD = BM + 8;      // padded rows per column
            constexpr int TPC  = BM / 8;      // threads per column (8 u16 each)
            constexpr int CPI  = 256 / TPC;   // columns per write iter
            static_assert(BN * TPAD <= 2 * KSUB * (ASZ + BSZ), "T fits smem");
            u16* T = smem;                    // [BN][TPAD] u16
            __syncthreads();                  // all waves done reading As/Bs
#pragma unroll
            for (int y = 0; y < NT; ++y) {
                const int crel = wn * (NT * 16) + y * 16 + l16;
                const float bval = g.bv[n0 - 1024 + crel];
#pragma unroll
                for (int x = 0; x < TM; ++x)
#pragma unroll
                    for (int r = 0; r < 4; ++r) {
                        const int rrel = wm * (TM * 16) + x * 16 + quad * 4 + r;
                        T[crel * TPAD + rrel] = f2bf(acc[x][y][r] + bval);
                    }
            }
            __syncthreads();
            const int vb  = m0 >> 11;         // batch (BM divides 2048)
            const int pos = m0 & 2047;
            u16* dst = g.vTd + (long)vb * (512l * 2048) + (long)(n0 - 1024) * 2048 + pos;
#pragma unroll
            for (int i = 0; i < BN / CPI; ++i) {
                const int c  = i * CPI + (t / TPC);
                const int ms = (t % TPC) * 8;
                *(u16x8*)(dst + (long)c * 2048 + ms) = *(const u16x8*)&T[c * TPAD + ms];
            }
            return;
        }
    }

    // CMODE 4: compute 1/l into smem (reused; K-loop done) before the C-write.
    float* invp = (float*)smem;
    if constexpr (CMODE == 4) {
        __syncthreads();                  // all waves done reading As/Bs
        if (t < BM) {
            float l = 0.0f;
#pragma unroll
            for (int j = 0; j < 16; ++j)
                l += g.lsum[(long)j * 8192 + batch * 2048 + m0 + t];
            invp[t] = 1.0f / l;
        }
        __syncthreads();
    }

    float rs[TM][4];
    if (CMODE == 3)
#pragma unroll
        for (int x = 0; x < TM; ++x)
#pragma unroll
            for (int r = 0; r < 4; ++r) rs[x][r] = 0.0f;

#pragma unroll
    for (int y = 0; y < NT; ++y) {
        const int col = n0 + wn * (NT * 16) + y * 16 + l16;
        float bval = 0.0f;
        if (CMODE == 2)
            bval = col < 512 ? g.bq[col] : g.bk[col - 512];
        else if (EPI >= 1)
            bval = g.bias[col];
#pragma unroll
        for (int x = 0; x < TM; ++x) {
#pragma unroll
            for (int r = 0; r < 4; ++r) {
                const int row = m0 + wm * (TM * 16) + x * 16 + quad * 4 + r;
                float v = acc[x][y][r] * g.scale + bval;
                if (EPI == 2) v = 0.5f * v * (1.0f + erff(v * 0.70710678118654752f));
                if (CMODE == 3) {
                    const float e = __expf(v);
                    rs[x][r] += e;
                    ((u16*)g.C + g.strC * batch)[(long)row * g.ldc + col] = f2bf(e);
                } else if (CMODE == 2) {
                    u16* dst = col < 512 ? g.qd : g.kd;
                    dst[(long)row * 512 + (col & 511)] = f2bf(v);
                } else if (CMODE == 4) {
                    ((float*)g.C + g.strC * batch)[(long)row * g.ldc + col] = v * invp[row - m0];
                } else if (SPLITK) {
                    float* dst = kh ? g.Cpart : (float*)g.C;
                    dst[g.strC * batch + (long)row * g.ldc + col] = v;
                } else if (CMODE == 1) {
                    ((float*)g.C + g.strC * batch)[(long)row * g.ldc + col] = v;
                } else {
                    ((u16*)g.C + g.strC * batch)[(long)row * g.ldc + col] = f2bf(v);
                }
            }
        }
    }

    if (CMODE == 3) {
        const int nslot = 2 * (n0 / BN) + wn;   // logical n-tile slot (XSW-safe)
#pragma unroll
        for (int x = 0; x < TM; ++x) {
#pragma unroll
            for (int r = 0; r < 4; ++r) {
                float s = rs[x][r];
                s += __shfl_xor(s, 1, 64);
                s += __shfl_xor(s, 2, 64);
                s += __shfl_xor(s, 4, 64);
                s += __shfl_xor(s, 8, 64);
                if (l16 == 0) {
                    const int row = m0 + wm * (TM * 16) + x * 16 + quad * 4 + r;
                    g.lsum[(long)nslot * 8192 + batch * 2048 + row] = s;
                }
            }
        }
    }
}

extern "C" void kernel_launch(void* const* d_in, const int* in_sizes, int n_in,
                              void* d_out, int out_size, void* d_ws, size_t ws_size,
                              hipStream_t stream)
{
    const int*   tok = (const int*)d_in[0];
    const float* emb = (const float*)d_in[1];
    const float* W1  = (const float*)d_in[2];
    const float* b1  = (const float*)d_in[3];
    const float* Wq  = (const float*)d_in[4];
    const float* bq  = (const float*)d_in[5];
    const float* Wk  = (const float*)d_in[6];
    const float* bk  = (const float*)d_in[7];
    const float* Wv  = (const float*)d_in[8];
    const float* bv  = (const float*)d_in[9];
    float* out = (float*)d_out;

    u16* act   = (u16*)d_out;                  // [8192][512] bf16 (8 MiB)
    u16* wbase = act + 8192l * 512;
    u16* W1T = wbase;                          // [512][256]
    u16* WqT = wbase + 131072;                 // [1536][512] contiguous
    u16* WkT = WqT + 262144;
    u16* WvT = WkT + 262144;

    char* ws = (char*)d_ws;
    u16* q     = (u16*)(ws);
    u16* k     = (u16*)(ws + (8l  << 20));
    u16* vT    = (u16*)(ws + (16l << 20));     // [4][512][2048]
    u16* sc    = (u16*)(ws + (24l << 20));     // 32 MiB (e values)
    float* lsum = (float*)(ws + (56l << 20));  // [16][8192] f32
    u16* embB  = sc;                           // dead before sc written

    const dim3 blk(256);
    const float iscl = 0.044194173824159216f;  // 1/sqrt(512)
    const long  TB = 2048l * 512;
    const long  SS = 2048l * 2048;

    // 0. prep: weight transposes (z<4) + XCD-striped gather+cvt (z>=4)
    PArgs p;
    p.wsrc[0] = W1; p.wsrc[1] = Wq; p.wsrc[2] = Wk; p.wsrc[3] = Wv;
    p.wdst[0] = W1T; p.wdst[1] = WqT; p.wdst[2] = WkT; p.wdst[3] = WvT;
    p.wK[0] = 256; p.wK[1] = 512; p.wK[2] = 512; p.wK[3] = 512;
    p.emb = emb; p.tok = tok; p.embB = embB;
    prep_k<<<dim3(8, 8, 20), blk, 0, stream>>>(p);

    // 1. act = gelu(embB @ W1T + b1)   M=8192 N=512 K=256  TM=2 NT=4 KSUB=2
    {
        GArgs a = {};
        a.A = embB; a.B = W1T; a.bias = b1; a.C = act;
        a.K = 256; a.lda = 256; a.ldb = 256; a.ldc = 512; a.scale = 1.0f;
        gemm128<2, 4, 2, 2, 2, 0, false, false, true><<<dim3(4, 128, 1), blk, 0, stream>>>(a);
    }
    // 2. fused QKV   M=8192 N=1536 K=512  TM=4 NT=4 KSUB=2 (BM=BN=128, BK=64)
    //    grid (12,64) XSW = 768 blocks, LDS 64KiB -> 2/CU, 32 MFMA/barrier.
    {
        GArgs a = {};
        a.A = act; a.B = WqT; a.K = 512; a.lda = 512; a.ldb = 512; a.scale = 1.0f;
        a.qd = q; a.kd = k; a.vTd = vT; a.bq = bq; a.bk = bk; a.bv = bv;
        gemm128<4, 4, 2, 2, 0, 2, false, false, true><<<dim3(12, 64, 1), blk, 0, stream>>>(a);
    }
    // 3. e = exp(q @ k^T / sqrt(512)) + row sums   M=N=2048 K=512  TM=4 BN=256
    //    XSW: grid (8,16,4), mper=2; lsum slot 2*(n0/BN)+wn (XSW-safe).
    {
        GArgs a = {};
        a.A = q; a.B = k; a.C = sc; a.lsum = lsum;
        a.K = 512; a.lda = 512; a.ldb = 512; a.ldc = 2048;
        a.strA = TB; a.strB = TB; a.strC = SS; a.scale = iscl;
        gemm128<4, 8, 1, 2, 0, 3, false, false, true><<<dim3(8, 16, 4), blk, 0, stream>>>(a);
    }
    // 4. out = (e @ vT^T) / l_row   M=2048 N=512 K=2048  TM=4 NT=4 KSUB=4
    //    XSW grid (4,16,4) = 256 blocks (1/CU, OCC=1), BK=128, LDS 128KiB:
    //    64 MFMA/barrier, 16 barriers; per-CU staged bytes 1.5 -> 1.0 MB.
    {
        GArgs a = {};
        a.A = sc; a.B = vT; a.C = out; a.lsum = lsum;
        a.K = 2048; a.lda = 2048; a.ldb = 2048; a.ldc = 512;
        a.strA = SS; a.strB = TB; a.strC = TB; a.scale = 1.0f;
        gemm128<4, 4, 4, 1, 0, 4, false, false, true><<<dim3(4, 16, 4), blk, 0, stream>>>(a);
    }
}

// Round 18
// 185.193 us; speedup vs baseline: 1.0219x; 1.0012x over previous
//
#include <hip/hip_runtime.h>
#include <math.h>

// ToyModel: B=4, S=2048, E=256, H=512, VOCAB=50257.
// Inputs/output f32; intermediates bf16; MFMA bf16 w/ f32 accum. posneg == identity.
//
// Round 25: PIPE=1 counted-vmcnt ring on PV at 1 block/CU. r24's null
// refuted "staging-BW-bound": at 256 blocks (1/CU) every barrier exposes
// full fill latency (no co-resident block to overlap, m114). r15's PIPE=1
// null was at 2/CU where overlap already existed — wrong regime. PV now:
// TM=4 NT=4 KSUB=2 PIPE=1, 3-buffer ring 96KiB, depth-2 prefetch, counted
// s_waitcnt vmcnt(8) (LPS=(TM/2+NT/2)*KSUB=8, literal derived via constexpr).
// Ring code = r15's proven path. Rest = r23/r24 best (185.4): s2 128²
// KSUB=2, s3 XSW + XSW-safe lsum slot, s1 KSUB=2, CMODE=4 smem normalizer.
//
// Ledger: KSUB/bigger-tile wins 4x; tile-shrink loss; read-swizzle null;
// PIPE null at 2/CU; QK write-repack loss; QK XCD-swizzle null; PV
// XCD-swizzle small win; PV 128² KSUB=4 @1/CU null (drain-exposed).
//
// ws: q@0 | k@8MiB | vT@16MiB | sc@24MiB(32MiB) | lsum@56MiB(512KB).
// embB aliases sc (dead before sc written).

typedef unsigned short u16;
typedef u16   u16x8 __attribute__((ext_vector_type(8)));
typedef short s16x8 __attribute__((ext_vector_type(8)));
typedef float f32x4 __attribute__((ext_vector_type(4)));
typedef float f32x8 __attribute__((ext_vector_type(8)));

static __device__ __forceinline__ u16 f2bf(float f) {
    unsigned u = __builtin_bit_cast(unsigned, f);
    u = (u + 0x7fffu + ((u >> 16) & 1u)) >> 16;   // RNE
    return (u16)u;
}

static __device__ __forceinline__ void gload_lds16(const u16* g, u16* l) {
    __builtin_amdgcn_global_load_lds(
        (const __attribute__((address_space(1))) void*)g,
        (__attribute__((address_space(3))) void*)l, 16, 0, 0);
}

struct PArgs {
    const float* wsrc[4];
    u16*         wdst[4];
    int          wK[4];
    const float* emb;
    const int*   tok;
    u16*         embB;
};

// z<4: f32 W[K][512] -> bf16 WT[512][K]. z>=4: XCD-striped gather+cvt of emb rows.
__launch_bounds__(256)
__global__ void prep_k(PArgs p)
{
    const int z = blockIdx.z;
    if (z < 4) {
        const float* W = p.wsrc[z];
        u16* WT = p.wdst[z];
        const int K = p.wK[z];
        const int c0 = blockIdx.x * 64;
        const int r0 = blockIdx.y * 64;
        if (r0 >= K) return;
        __shared__ float T[64][65];
        const int t = threadIdx.x;
        const int col = t & 63;
        const int rb  = t >> 6;
#pragma unroll
        for (int i = 0; i < 16; ++i)
            T[i * 4 + rb][col] = W[(long)(r0 + i * 4 + rb) * 512 + c0 + col];
        __syncthreads();
#pragma unroll
        for (int i = 0; i < 16; ++i) {
            const int orow = i * 4 + rb;
            WT[(long)(c0 + orow) * K + r0 + col] = f2bf(T[col][orow]);
        }
    } else {
        const int b = (z - 4) * 64 + blockIdx.y * 8 + blockIdx.x;   // 0..1023
        const int g = (b & 7) * 128 + (b >> 3);
        const int t = g * 2048 + threadIdx.x * 8;
        const int row = t >> 8;
        const int c8  = t & 255;
        f32x8 v = *(const f32x8*)(p.emb + (long)p.tok[row] * 256 + c8);
        u16x8 o;
#pragma unroll
        for (int j = 0; j < 8; ++j) o[j] = f2bf(v[j]);
        *(u16x8*)(p.embB + (long)row * 256 + c8) = o;
    }
}

struct GArgs {
    const u16* A; const u16* B; const float* bias; void* C;
    float* Cpart;
    float* lsum;                          // [16][8192] QK row partial sums
    u16 *qd, *kd, *vTd;
    const float *bq, *bk, *bv;
    int K, lda, ldb, ldc;
    long strA, strB, strC;
    float scale;
};

// MFMA GEMM. BM=TM*32, BN=NT*32, BK=32*KSUB. 4 waves 2x2.
// KSUB: BK=32 slabs staged together (LDS [KSUB][rows][32]).
// OCC: __launch_bounds__ min waves/EU.
// PIPE: 0 = classic dbuf + __syncthreads (vmcnt(0) drain per tile);
//       1 = 3-buffer ring, prefetch depth 2, counted s_waitcnt vmcnt(LPS) +
//           raw s_barrier (prefetched loads stay in flight across barriers).
// EPI: 0 scale, 1 +bias, 2 +bias+GELU.
// CMODE: 0 bf16 C, 1 f32 C, 2 QKV-fused (n0<1024: q/k row-major; n0>=1024:
//        v repacked via LDS [BN][BM+8] -> vT[batch][h][pos]), 3 QK+exp
//        (lsum slot = 2*(n0/BN)+wn, XSW-safe), 4 f32 C normalized by 1/l
//        (epilogue smem reuse).
// MX: m-tile fastest. SPLITK: z=batch*2+kh, K half = 1024. XSW: XCD m-stripes.
template <int TM, int NT, int KSUB, int OCC, int PIPE, int EPI, int CMODE,
          bool MX, bool SPLITK, bool XSW>
__launch_bounds__(256, OCC)
__global__ void gemm128(GArgs g)
{
    constexpr int BM  = TM * 32;
    constexpr int BN  = NT * 32;
    constexpr int ASZ = BM * 32;          // one BK=32 slab
    constexpr int BSZ = BN * 32;
    constexpr int BK  = 32 * KSUB;
    constexpr int NBUF = (PIPE == 1) ? 3 : 2;
    constexpr int LPS  = (TM / 2 + NT / 2) * KSUB;   // loads per stage
    static_assert(PIPE == 0 || LPS == 6 || LPS == 8,
                  "PIPE=1 vmcnt literal supports LPS 6 or 8");
    __shared__ u16 smem[NBUF * KSUB * (ASZ + BSZ)];
    u16* As = smem;
    u16* Bs = smem + NBUF * KSUB * ASZ;

    const int bz    = blockIdx.z;
    const int batch = SPLITK ? (bz >> 1) : bz;
    const int kh    = SPLITK ? (bz & 1) : 0;
    const u16* A = g.A + g.strA * batch + (SPLITK ? kh * 1024 : 0);
    const u16* B = g.B + g.strB * batch + (SPLITK ? kh * 1024 : 0);

    int m0, n0;
    if (XSW) {
        const int lid = blockIdx.y * gridDim.x + blockIdx.x;
        const int xcd = lid & 7;
        const int j   = lid >> 3;
        const int mper = gridDim.y >> 3;
        m0 = (xcd * mper + (j % mper)) * BM;
        n0 = (j / mper) * BN;
    } else {
        m0 = (MX ? blockIdx.x : blockIdx.y) * BM;
        n0 = (MX ? blockIdx.y : blockIdx.x) * BN;
    }

    const int t = threadIdx.x;
    const int w = t >> 6;
    const int lane = t & 63;
    const int quad = lane >> 4;
    const int l16  = lane & 15;
    const int wm = w >> 1, wn = w & 1;

    const int srow = w * 16 + (lane >> 2);
    const int skc  = (lane & 3) * 8;
    const u16* ga = A + (long)(m0 + srow) * g.lda + skc;
    const u16* gb = B + (long)(n0 + srow) * g.ldb + skc;
    const long a64 = (long)64 * g.lda;
    const long b64 = (long)64 * g.ldb;

    auto stage = [&](int buf, int k0) {
#pragma unroll
        for (int s = 0; s < KSUB; ++s) {
            u16* la = As + (buf * KSUB + s) * ASZ + w * 512;
            u16* lb = Bs + (buf * KSUB + s) * BSZ + w * 512;
#pragma unroll
            for (int i = 0; i < TM / 2; ++i)
                gload_lds16(ga + i * a64 + k0 + s * 32, la + i * 2048);
#pragma unroll
            for (int i = 0; i < NT / 2; ++i)
                gload_lds16(gb + i * b64 + k0 + s * 32, lb + i * 2048);
        }
    };

    f32x4 acc[TM][NT] = {};
    const int K = SPLITK ? 1024 : g.K;

    auto compute = [&](int buf) {
#pragma unroll
        for (int s = 0; s < KSUB; ++s) {
            const u16* as = As + (buf * KSUB + s) * ASZ;
            const u16* bs = Bs + (buf * KSUB + s) * BSZ;
            s16x8 af[TM], bf[NT];
#pragma unroll
            for (int x = 0; x < TM; ++x)
                af[x] = *(const s16x8*)&as[(wm * (TM * 16) + x * 16 + l16) * 32 + quad * 8];
#pragma unroll
            for (int y = 0; y < NT; ++y)
                bf[y] = *(const s16x8*)&bs[(wn * (NT * 16) + y * 16 + l16) * 32 + quad * 8];
#pragma unroll
            for (int x = 0; x < TM; ++x)
#pragma unroll
                for (int y = 0; y < NT; ++y)
                    acc[x][y] = __builtin_amdgcn_mfma_f32_16x16x32_bf16(af[x], bf[y], acc[x][y], 0, 0, 0);
        }
    };

    if constexpr (PIPE == 1) {
        const int nt = K / BK;
        stage(0, 0);
        if (nt > 1) stage(1, BK);
        for (int tt = 0; tt < nt; ++tt) {
            if (tt + 1 < nt) {
                if constexpr (LPS == 6) asm volatile("s_waitcnt vmcnt(6)" ::: "memory");
                else                    asm volatile("s_waitcnt vmcnt(8)" ::: "memory");
            } else {
                asm volatile("s_waitcnt vmcnt(0)" ::: "memory");
            }
            __builtin_amdgcn_s_barrier();
            __builtin_amdgcn_sched_barrier(0);   // pin: no gload hoists above barrier
            if (tt + 2 < nt) stage((tt + 2) % 3, (tt + 2) * BK);
            compute(tt % 3);
        }
    } else {
        stage(0, 0);
        int cur = 0;
        for (int k0 = 0; k0 < K; k0 += BK) {
            __syncthreads();
            if (k0 + BK < K) stage(cur ^ 1, k0 + BK);
            compute(cur);
            cur ^= 1;
        }
    }

    // ---- v-block epilogue (QKV fused, n0 >= 1024): LDS repack -> vT ----
    if constexpr (CMODE == 2) {
        if (n0 >= 1024) {
            constexpr int TPAD = BM + 8;      // padded rows per column
            constexpr int TPC  = BM / 8;      // threads per column (8 u16 each)
            constexpr int CPI  = 256 / TPC;   // columns per write iter
            static_assert(BN * TPAD <= NBUF * KSUB * (ASZ + BSZ), "T fits smem");
            u16* T = smem;                    // [BN][TPAD] u16
            __syncthreads();                  // all waves done reading As/Bs
#pragma unroll
            for (int y = 0; y < NT; ++y) {
                const int crel = wn * (NT * 16) + y * 16 + l16;
                const float bval = g.bv[n0 - 1024 + crel];
#pragma unroll
                for (int x = 0; x < TM; ++x)
#pragma unroll
                    for (int r = 0; r < 4; ++r) {
                        const int rrel = wm * (TM * 16) + x * 16 + quad * 4 + r;
                        T[crel * TPAD + rrel] = f2bf(acc[x][y][r] + bval);
                    }
            }
            __syncthreads();
            const int vb  = m0 >> 11;         // batch (BM divides 2048)
            const int pos = m0 & 2047;
            u16* dst = g.vTd + (long)vb * (512l * 2048) + (long)(n0 - 1024) * 2048 + pos;
#pragma unroll
            for (int i = 0; i < BN / CPI; ++i) {
                const int c  = i * CPI + (t / TPC);
                const int ms = (t % TPC) * 8;
                *(u16x8*)(dst + (long)c * 2048 + ms) = *(const u16x8*)&T[c * TPAD + ms];
            }
            return;
        }
    }

    // CMODE 4: compute 1/l into smem (reused; K-loop done) before the C-write.
    float* invp = (float*)smem;
    if constexpr (CMODE == 4) {
        __syncthreads();                  // all waves done reading As/Bs
        if (t < BM) {
            float l = 0.0f;
#pragma unroll
            for (int j = 0; j < 16; ++j)
                l += g.lsum[(long)j * 8192 + batch * 2048 + m0 + t];
            invp[t] = 1.0f / l;
        }
        __syncthreads();
    }

    float rs[TM][4];
    if (CMODE == 3)
#pragma unroll
        for (int x = 0; x < TM; ++x)
#pragma unroll
            for (int r = 0; r < 4; ++r) rs[x][r] = 0.0f;

#pragma unroll
    for (int y = 0; y < NT; ++y) {
        const int col = n0 + wn * (NT * 16) + y * 16 + l16;
        float bval = 0.0f;
        if (CMODE == 2)
            bval = col < 512 ? g.bq[col] : g.bk[col - 512];
        else if (EPI >= 1)
            bval = g.bias[col];
#pragma unroll
        for (int x = 0; x < TM; ++x) {
#pragma unroll
            for (int r = 0; r < 4; ++r) {
                const int row = m0 + wm * (TM * 16) + x * 16 + quad * 4 + r;
                float v = acc[x][y][r] * g.scale + bval;
                if (EPI == 2) v = 0.5f * v * (1.0f + erff(v * 0.70710678118654752f));
                if (CMODE == 3) {
                    const float e = __expf(v);
                    rs[x][r] += e;
                    ((u16*)g.C + g.strC * batch)[(long)row * g.ldc + col] = f2bf(e);
                } else if (CMODE == 2) {
                    u16* dst = col < 512 ? g.qd : g.kd;
                    dst[(long)row * 512 + (col & 511)] = f2bf(v);
                } else if (CMODE == 4) {
                    ((float*)g.C + g.strC * batch)[(long)row * g.ldc + col] = v * invp[row - m0];
                } else if (SPLITK) {
                    float* dst = kh ? g.Cpart : (float*)g.C;
                    dst[g.strC * batch + (long)row * g.ldc + col] = v;
                } else if (CMODE == 1) {
                    ((float*)g.C + g.strC * batch)[(long)row * g.ldc + col] = v;
                } else {
                    ((u16*)g.C + g.strC * batch)[(long)row * g.ldc + col] = f2bf(v);
                }
            }
        }
    }

    if (CMODE == 3) {
        const int nslot = 2 * (n0 / BN) + wn;   // logical n-tile slot (XSW-safe)
#pragma unroll
        for (int x = 0; x < TM; ++x) {
#pragma unroll
            for (int r = 0; r < 4; ++r) {
                float s = rs[x][r];
                s += __shfl_xor(s, 1, 64);
                s += __shfl_xor(s, 2, 64);
                s += __shfl_xor(s, 4, 64);
                s += __shfl_xor(s, 8, 64);
                if (l16 == 0) {
                    const int row = m0 + wm * (TM * 16) + x * 16 + quad * 4 + r;
                    g.lsum[(long)nslot * 8192 + batch * 2048 + row] = s;
                }
            }
        }
    }
}

extern "C" void kernel_launch(void* const* d_in, const int* in_sizes, int n_in,
                              void* d_out, int out_size, void* d_ws, size_t ws_size,
                              hipStream_t stream)
{
    const int*   tok = (const int*)d_in[0];
    const float* emb = (const float*)d_in[1];
    const float* W1  = (const float*)d_in[2];
    const float* b1  = (const float*)d_in[3];
    const float* Wq  = (const float*)d_in[4];
    const float* bq  = (const float*)d_in[5];
    const float* Wk  = (const float*)d_in[6];
    const float* bk  = (const float*)d_in[7];
    const float* Wv  = (const float*)d_in[8];
    const float* bv  = (const float*)d_in[9];
    float* out = (float*)d_out;

    u16* act   = (u16*)d_out;                  // [8192][512] bf16 (8 MiB)
    u16* wbase = act + 8192l * 512;
    u16* W1T = wbase;                          // [512][256]
    u16* WqT = wbase + 131072;                 // [1536][512] contiguous
    u16* WkT = WqT + 262144;
    u16* WvT = WkT + 262144;

    char* ws = (char*)d_ws;
    u16* q     = (u16*)(ws);
    u16* k     = (u16*)(ws + (8l  << 20));
    u16* vT    = (u16*)(ws + (16l << 20));     // [4][512][2048]
    u16* sc    = (u16*)(ws + (24l << 20));     // 32 MiB (e values)
    float* lsum = (float*)(ws + (56l << 20));  // [16][8192] f32
    u16* embB  = sc;                           // dead before sc written

    const dim3 blk(256);
    const float iscl = 0.044194173824159216f;  // 1/sqrt(512)
    const long  TB = 2048l * 512;
    const long  SS = 2048l * 2048;

    // 0. prep: weight transposes (z<4) + XCD-striped gather+cvt (z>=4)
    PArgs p;
    p.wsrc[0] = W1; p.wsrc[1] = Wq; p.wsrc[2] = Wk; p.wsrc[3] = Wv;
    p.wdst[0] = W1T; p.wdst[1] = WqT; p.wdst[2] = WkT; p.wdst[3] = WvT;
    p.wK[0] = 256; p.wK[1] = 512; p.wK[2] = 512; p.wK[3] = 512;
    p.emb = emb; p.tok = tok; p.embB = embB;
    prep_k<<<dim3(8, 8, 20), blk, 0, stream>>>(p);

    // 1. act = gelu(embB @ W1T + b1)   M=8192 N=512 K=256  TM=2 NT=4 KSUB=2
    {
        GArgs a = {};
        a.A = embB; a.B = W1T; a.bias = b1; a.C = act;
        a.K = 256; a.lda = 256; a.ldb = 256; a.ldc = 512; a.scale = 1.0f;
        gemm128<2, 4, 2, 2, 0, 2, 0, false, false, true><<<dim3(4, 128, 1), blk, 0, stream>>>(a);
    }
    // 2. fused QKV   M=8192 N=1536 K=512  TM=4 NT=4 KSUB=2 (BM=BN=128, BK=64)
    //    grid (12,64) XSW = 768 blocks, LDS 64KiB -> 2/CU, 32 MFMA/barrier.
    {
        GArgs a = {};
        a.A = act; a.B = WqT; a.K = 512; a.lda = 512; a.ldb = 512; a.scale = 1.0f;
        a.qd = q; a.kd = k; a.vTd = vT; a.bq = bq; a.bk = bk; a.bv = bv;
        gemm128<4, 4, 2, 2, 0, 0, 2, false, false, true><<<dim3(12, 64, 1), blk, 0, stream>>>(a);
    }
    // 3. e = exp(q @ k^T / sqrt(512)) + row sums   M=N=2048 K=512  TM=4 BN=256
    //    XSW: grid (8,16,4), mper=2; lsum slot 2*(n0/BN)+wn (XSW-safe).
    {
        GArgs a = {};
        a.A = q; a.B = k; a.C = sc; a.lsum = lsum;
        a.K = 512; a.lda = 512; a.ldb = 512; a.ldc = 2048;
        a.strA = TB; a.strB = TB; a.strC = SS; a.scale = iscl;
        gemm128<4, 8, 1, 2, 0, 0, 3, false, false, true><<<dim3(8, 16, 4), blk, 0, stream>>>(a);
    }
    // 4. out = (e @ vT^T) / l_row   M=2048 N=512 K=2048  TM=4 NT=4 KSUB=2
    //    PIPE=1: 3-buffer ring 96KiB (1/CU), depth-2 prefetch, vmcnt(8).
    //    XSW grid (4,16,4) = 256 blocks, mper=2; normalize via smem 1/l.
    {
        GArgs a = {};
        a.A = sc; a.B = vT; a.C = out; a.lsum = lsum;
        a.K = 2048; a.lda = 2048; a.ldb = 2048; a.ldc = 512;
        a.strA = SS; a.strB = TB; a.strC = TB; a.scale = 1.0f;
        gemm128<4, 4, 2, 1, 1, 0, 4, false, false, true><<<dim3(4, 16, 4), blk, 0, stream>>>(a);
    }
}